// Round 8
// baseline (405.846 us; speedup 1.0000x reference)
//
#include <hip/hip_runtime.h>
#include <stdint.h>

#define B_SZ 2
#define S_LEN 2048
#define D_DIM 2048
#define NHEAD 16
#define HD 128
#define HALF 64
#define MROWS (B_SZ * S_LEN)   // 4096

typedef __attribute__((ext_vector_type(8))) __bf16 bf16x8;
typedef __attribute__((ext_vector_type(8))) unsigned short u16x8;
typedef __attribute__((ext_vector_type(4))) float f32x4;
typedef __attribute__((ext_vector_type(16))) float f32x16;
typedef __attribute__((ext_vector_type(4))) unsigned int u32x4;

__device__ inline unsigned short f2bf(float x) {
  union { float f; uint32_t u; } c; c.f = x;
  uint32_t r = (c.u + 0x7fffu + ((c.u >> 16) & 1u)) >> 16;
  return (unsigned short)r;
}

__device__ inline float bf2f(unsigned short b) {
  union { uint32_t u; float f; } c; c.u = (uint32_t)b << 16;
  return c.f;
}

__device__ inline void gll16(const void* g, void* l) {
  __builtin_amdgcn_global_load_lds(
      (const __attribute__((address_space(1))) void*)g,
      (__attribute__((address_space(3))) void*)l,
      16, 0, 0);
}

// ---------------- fused cast f32 -> bf16 for x + 4 weight matrices ----------------
__global__ void cast_all(const float* __restrict__ x,
                         const float* __restrict__ qw, const float* __restrict__ kw,
                         const float* __restrict__ vw, const float* __restrict__ ow,
                         unsigned short* __restrict__ xb,
                         unsigned short* __restrict__ qwb, unsigned short* __restrict__ kwb,
                         unsigned short* __restrict__ vwb, unsigned short* __restrict__ owb) {
  const int n_x = (MROWS * D_DIM) / 4;
  const int n_w = (D_DIM * D_DIM) / 4;      // == 1<<20
  const int total = n_x + 4 * n_w;
  int i = blockIdx.x * blockDim.x + threadIdx.x;
  int stride = gridDim.x * blockDim.x;
  for (; i < total; i += stride) {
    const float* src; unsigned short* dst; int off;
    if (i < n_x) { src = x; dst = xb; off = i; }
    else {
      int j = i - n_x;
      int seg = j >> 20;
      off = j & (n_w - 1);
      src = seg == 0 ? qw : seg == 1 ? kw : seg == 2 ? vw : ow;
      dst = seg == 0 ? qwb : seg == 1 ? kwb : seg == 2 ? vwb : owb;
    }
    float4 v = reinterpret_cast<const float4*>(src)[off];
    ushort4 o;
    o.x = f2bf(v.x); o.y = f2bf(v.y); o.z = f2bf(v.z); o.w = f2bf(v.w);
    reinterpret_cast<ushort4*>(dst)[off] = o;
  }
}

// ---------------- GEMM: C[i,j] = sum_k A[i,k]*Bt[j,k] + bias[j] ----------------
// MODE 0: fp32 linear. MODE 1: bf16 linear.
// MODE 2: bf16 s-tiled per-head transpose: Vt2[b][h][s/64][d][s%64]
template <int MODE>
__global__ __launch_bounds__(256) void gemm_bt(
    const unsigned short* __restrict__ A, const unsigned short* __restrict__ Bt,
    const float* __restrict__ bias, void* __restrict__ Cv,
    int M, int N, int K) {
  __shared__ __align__(16) unsigned short As[128 * 32];
  __shared__ __align__(16) unsigned short Bs[128 * 32];
  const int tid = threadIdx.x;
  const int lane = tid & 63;
  const int wave = tid >> 6;
  const int nbn = N >> 7;
  const int chunk = gridDim.x >> 3;
  const int lin = (blockIdx.x & 7) * chunk + (blockIdx.x >> 3);
  const int bm = lin / nbn, bn = lin - bm * nbn;
  const int wr = wave >> 1, wc = wave & 1;
  const int lm = lane & 15, lg = lane >> 4;

  f32x4 acc[4][4] = {};

  for (int k0 = 0; k0 < K; k0 += 32) {
    __syncthreads();
#pragma unroll
    for (int j = 0; j < 2; ++j) {
      int ob = wave * 2048 + j * 1024;
      int o = ob + lane * 16;
      int row = o >> 6;
      int col = (o & 63) >> 1;
      const unsigned short* ga = A + (size_t)(bm * 128 + row) * K + k0 + col;
      gll16(ga, (char*)As + ob);
      const unsigned short* gb = Bt + (size_t)(bn * 128 + row) * K + k0 + col;
      gll16(gb, (char*)Bs + ob);
    }
    __syncthreads();

    bf16x8 af[4], bfr[4];
#pragma unroll
    for (int mi = 0; mi < 4; ++mi)
      af[mi] = *reinterpret_cast<const bf16x8*>(
          &As[(wr * 64 + mi * 16 + lm) * 32 + lg * 8]);
#pragma unroll
    for (int ni = 0; ni < 4; ++ni)
      bfr[ni] = *reinterpret_cast<const bf16x8*>(
          &Bs[(wc * 64 + ni * 16 + lm) * 32 + lg * 8]);
#pragma unroll
    for (int mi = 0; mi < 4; ++mi)
#pragma unroll
      for (int ni = 0; ni < 4; ++ni)
        acc[mi][ni] = __builtin_amdgcn_mfma_f32_16x16x32_bf16(
            af[mi], bfr[ni], acc[mi][ni], 0, 0, 0);
  }

#pragma unroll
  for (int ni = 0; ni < 4; ++ni) {
    int col = bn * 128 + wc * 64 + ni * 16 + lm;
    float bv = bias[col];
    if constexpr (MODE == 2) {
      int h = col >> 7, d = col & (HD - 1);
#pragma unroll
      for (int mi = 0; mi < 4; ++mi) {
        int row0 = bm * 128 + wr * 64 + mi * 16 + lg * 4;
        int b = row0 >> 11, s0 = row0 & (S_LEN - 1);
        ushort4 o;
        o.x = f2bf(acc[mi][ni][0] + bv);
        o.y = f2bf(acc[mi][ni][1] + bv);
        o.z = f2bf(acc[mi][ni][2] + bv);
        o.w = f2bf(acc[mi][ni][3] + bv);
        unsigned short* vt = (unsigned short*)Cv;
        size_t oi = ((((size_t)(b * NHEAD + h) * (S_LEN / 64) + (s0 >> 6)) * HD + d) << 6)
                    + (s0 & 63);
        *reinterpret_cast<ushort4*>(vt + oi) = o;
      }
    } else {
#pragma unroll
      for (int mi = 0; mi < 4; ++mi) {
#pragma unroll
        for (int r = 0; r < 4; ++r) {
          int row = bm * 128 + wr * 64 + mi * 16 + lg * 4 + r;
          float v = acc[mi][ni][r] + bv;
          if constexpr (MODE == 1)
            ((unsigned short*)Cv)[(size_t)row * N + col] = f2bf(v);
          else
            ((float*)Cv)[(size_t)row * N + col] = v;
        }
      }
    }
  }
}

// ---------------- RMSNorm (full D) + RoPE, bf16 in -> bf16 out, * outscale ----------------
// BLOCKED=0: linear [row][D]. BLOCKED=1: head-blocked Kh[b][h][s][d].
template <int BLOCKED>
__global__ __launch_bounds__(256) void norm_rope(
    const unsigned short* __restrict__ h, const float* __restrict__ w,
    const float* __restrict__ cosb, const float* __restrict__ sinb,
    unsigned short* __restrict__ out, float outscale) {
  const int row = blockIdx.x;
  const int pos = row & (S_LEN - 1);
  const unsigned short* hr = h + (size_t)row * D_DIM;
  const int t = threadIdx.x;
  const int d = t * 8;

  u16x8 hv = *reinterpret_cast<const u16x8*>(hr + d);
  float a[8];
#pragma unroll
  for (int i = 0; i < 8; ++i) a[i] = bf2f(hv[i]);
  float ss = 0.f;
#pragma unroll
  for (int i = 0; i < 8; ++i) ss += a[i] * a[i];
#pragma unroll
  for (int off = 32; off > 0; off >>= 1) ss += __shfl_down(ss, off);
  __shared__ float red[4];
  if ((t & 63) == 0) red[t >> 6] = ss;
  __syncthreads();
  float tot = red[0] + red[1] + red[2] + red[3];
  float inv = rsqrtf(tot * (1.0f / D_DIM) + 1e-6f) * outscale;

  const int p = (d & (HD - 1)) >> 1;
  const float* cp = cosb + pos * HALF + p;
  const float* sp = sinb + pos * HALF + p;
  const float* wp = w + d;

  float c0 = cp[0], c1 = cp[1], c2 = cp[2], c3 = cp[3];
  float s0 = sp[0], s1 = sp[1], s2 = sp[2], s3 = sp[3];
#pragma unroll
  for (int i = 0; i < 8; ++i) a[i] = a[i] * inv * wp[i];
  u16x8 o;
  o[0] = f2bf(a[0] * c0 - a[1] * s0);
  o[1] = f2bf(a[0] * s0 + a[1] * c0);
  o[2] = f2bf(a[2] * c1 - a[3] * s1);
  o[3] = f2bf(a[2] * s1 + a[3] * c1);
  o[4] = f2bf(a[4] * c2 - a[5] * s2);
  o[5] = f2bf(a[4] * s2 + a[5] * c2);
  o[6] = f2bf(a[6] * c3 - a[7] * s3);
  o[7] = f2bf(a[6] * s3 + a[7] * c3);
  if constexpr (BLOCKED) {
    int hh = t >> 4;            // head = d / HD
    int dd = d & (HD - 1);
    size_t oi = (((size_t)((row >> 11) * NHEAD + hh) * S_LEN) + pos) * HD + dd;
    *reinterpret_cast<u16x8*>(out + oi) = o;
  } else {
    *reinterpret_cast<u16x8*>(out + (size_t)row * D_DIM + d) = o;
  }
}

// ---------------- flash attention: 4 waves x 32q (32x32 MFMA), KVBLK=64 ----------------
// LDS diet for 3 blocks/CU: K double-buffered (32KB) + V single-buffered (16KB).
// Per tile: issue V(t)-stage then K(t+1)-stage; vmcnt(8) drains K(t) [oldest];
// after QK+softmax, vmcnt(4) drains V(t) [leaves K(t+1) in flight]; 3 barriers.
// Swapped QK^T; in-register P via cvt_pk+permlane; defer-max (THR=8, exp2 domain).
__global__ __launch_bounds__(256, 3) void attn_kernel(
    const unsigned short* __restrict__ Q, const unsigned short* __restrict__ Kh,
    const unsigned short* __restrict__ Vt, unsigned short* __restrict__ O) {
  const int idx = blockIdx.x;
  const int swz = (idx & 7) * 64 + (idx >> 3);   // 512 blocks, 64/XCD
  const int qb = swz & 15;
  const int h = (swz >> 4) & 15;
  const int b = swz >> 8;

  const int tid = threadIdx.x;
  const int lane = tid & 63;
  const int wave = tid >> 6;
  const int l31 = lane & 31;
  const int hh = lane >> 5;

  const size_t qbase = (size_t)b * S_LEN * D_DIM + (size_t)h * HD;   // linear Q/O
  const size_t hbase = (size_t)(b * NHEAD + h) * S_LEN * HD;         // blocked K/V
  const int q0w = qb * 128 + wave * 32;

  __shared__ __align__(16) unsigned short Ks[2 * 64 * 128];  // 2 x 16KB (dbuf)
  __shared__ __align__(16) unsigned short Vs[128 * 64];      // 1 x 16KB

  bf16x8 qf[8];
#pragma unroll
  for (int ds_ = 0; ds_ < 8; ++ds_)
    qf[ds_] = *reinterpret_cast<const bf16x8*>(
        Q + qbase + (size_t)(q0w + l31) * D_DIM + ds_ * 16 + hh * 8);

  f32x16 oacc[4] = {};
  float mrow = -1e30f, lrow = 0.f;

  const int pbase = wave * 1024 + (lane << 4);

  auto stageK = [&](int buf, int tix) {
    const unsigned short* ksrc = Kh + hbase + (size_t)tix * (64 * HD);
#pragma unroll
    for (int j = 0; j < 4; ++j) {
      int p = pbase + j * 4096;
      int kr = p >> 8;                       // K row (256B rows)
      int kc = ((p >> 4) & 15) ^ (kr & 7);   // pre-swizzled source chunk
      gll16(ksrc + kr * 128 + kc * 8, (char*)Ks + buf * 16384 + p);
    }
  };
  auto stageV = [&](int tix) {
    const unsigned short* vsrc = Vt + hbase + (size_t)tix * (64 * HD);
#pragma unroll
    for (int j = 0; j < 4; ++j) {
      int p = pbase + j * 4096;
      int vr = p >> 7;                       // V d-row (128B rows)
      int vc = ((p >> 4) & 7) ^ (vr & 7);
      gll16(vsrc + vr * 64 + vc * 8, (char*)Vs + p);
    }
  };

  stageK(0, 0);   // 4 K-loads in flight

  const int NT = S_LEN / 64;
  for (int t = 0; t < NT; ++t) {
    const int cur = t & 1;
    stageV(t);                                          // +4 (V(t))
    stageK(cur ^ 1, (t + 1 < NT) ? t + 1 : t);          // +4 (K(t+1))
    asm volatile("s_waitcnt vmcnt(8)" ::: "memory");    // drain K(t) (oldest 4)
    __builtin_amdgcn_sched_barrier(0);
    __builtin_amdgcn_s_barrier();          // BAR1: K(t) visible to all waves
    __builtin_amdgcn_sched_barrier(0);

    // ---- QK^T swapped: pA = P[k=0..31][q], pB = P[k=32..63][q], q col = l31
    const char* kbp = (const char*)Ks + cur * 16384;
    f32x16 pA = {}, pB = {};
    __builtin_amdgcn_s_setprio(1);
#pragma unroll
    for (int ds_ = 0; ds_ < 8; ++ds_) {
      bf16x8 k0 = *reinterpret_cast<const bf16x8*>(
          kbp + l31 * 256 + (((ds_ * 2 + hh) ^ (l31 & 7)) << 4));
      bf16x8 k1 = *reinterpret_cast<const bf16x8*>(
          kbp + (32 + l31) * 256 + (((ds_ * 2 + hh) ^ (l31 & 7)) << 4));
      pA = __builtin_amdgcn_mfma_f32_32x32x16_bf16(k0, qf[ds_], pA, 0, 0, 0);
      pB = __builtin_amdgcn_mfma_f32_32x32x16_bf16(k1, qf[ds_], pB, 0, 0, 0);
    }
    __builtin_amdgcn_s_setprio(0);

    // ---- online softmax (per-lane q-row = l31)
    float mx = pA[0];
#pragma unroll
    for (int r = 1; r < 16; ++r) mx = fmaxf(mx, pA[r]);
#pragma unroll
    for (int r = 0; r < 16; ++r) mx = fmaxf(mx, pB[r]);
    mx = fmaxf(mx, __shfl_xor(mx, 32));
    if (__any(mx > mrow + 8.0f)) {          // defer-max rescale (rare)
      float nm = fmaxf(mrow, mx);
      float alpha = exp2f(mrow - nm);
      mrow = nm;
      lrow *= alpha;
#pragma unroll
      for (int r = 0; r < 16; ++r) {
        int qr = (r & 3) + 8 * (r >> 2) + 4 * hh;
        float av = __shfl(alpha, qr);
        oacc[0][r] *= av; oacc[1][r] *= av; oacc[2][r] *= av; oacc[3][r] *= av;
      }
    }
    float ls = 0.f;
#pragma unroll
    for (int r = 0; r < 16; ++r) { float v = exp2f(pA[r] - mrow); pA[r] = v; ls += v; }
#pragma unroll
    for (int r = 0; r < 16; ++r) { float v = exp2f(pB[r] - mrow); pB[r] = v; ls += v; }
    lrow += ls;

    // ---- P -> bf16 A-frags in-register (cvt_pk + permlane32_swap)
    uint32_t w[16];
#pragma unroll
    for (int gg = 0; gg < 4; ++gg) {
      uint32_t lo, hi;
      float a0 = pA[4 * gg], a1 = pA[4 * gg + 1], a2 = pA[4 * gg + 2], a3 = pA[4 * gg + 3];
      asm("v_cvt_pk_bf16_f32 %0, %1, %2" : "=v"(lo) : "v"(a0), "v"(a1));
      asm("v_cvt_pk_bf16_f32 %0, %1, %2" : "=v"(hi) : "v"(a2), "v"(a3));
      w[gg * 2] = lo; w[gg * 2 + 1] = hi;
    }
#pragma unroll
    for (int gg = 0; gg < 4; ++gg) {
      uint32_t lo, hi;
      float a0 = pB[4 * gg], a1 = pB[4 * gg + 1], a2 = pB[4 * gg + 2], a3 = pB[4 * gg + 3];
      asm("v_cvt_pk_bf16_f32 %0, %1, %2" : "=v"(lo) : "v"(a0), "v"(a1));
      asm("v_cvt_pk_bf16_f32 %0, %1, %2" : "=v"(hi) : "v"(a2), "v"(a3));
      w[8 + gg * 2] = lo; w[8 + gg * 2 + 1] = hi;
    }
    bf16x8 pa[4];
#pragma unroll
    for (int s = 0; s < 4; ++s) {
      int wb = (s >> 1) * 8 + (s & 1) * 4;
      uint32_t le = w[wb], he = w[wb + 1], lo_ = w[wb + 2], ho = w[wb + 3];
      asm("v_permlane32_swap_b32 %0, %1" : "+v"(le), "+v"(lo_));
      asm("v_permlane32_swap_b32 %0, %1" : "+v"(he), "+v"(ho));
      u32x4 fr = {le, he, lo_, ho};
      pa[s] = __builtin_bit_cast(bf16x8, fr);
    }

    // ---- wait V(t) (drains to 4: K(t+1) stays in flight), then barrier
    asm volatile("s_waitcnt vmcnt(4)" ::: "memory");
    __builtin_amdgcn_sched_barrier(0);
    __builtin_amdgcn_s_barrier();          // BAR-mid: V(t) visible to all waves
    __builtin_amdgcn_sched_barrier(0);

    // ---- PV: O[q][d] += P[q][k] V[k][d]
    const char* vbp = (const char*)Vs;
    __builtin_amdgcn_s_setprio(1);
#pragma unroll
    for (int db = 0; db < 4; ++db) {
      int d = db * 32 + l31;
#pragma unroll
      for (int ks = 0; ks < 4; ++ks) {
        bf16x8 vv = *reinterpret_cast<const bf16x8*>(
            vbp + d * 128 + (((ks * 2 + hh) ^ (d & 7)) << 4));
        oacc[db] = __builtin_amdgcn_mfma_f32_32x32x16_bf16(pa[ks], vv, oacc[db], 0, 0, 0);
      }
    }
    __builtin_amdgcn_s_setprio(0);

    __builtin_amdgcn_sched_barrier(0);
    __builtin_amdgcn_s_barrier();          // BAR2: Vs + Ks[cur] reads done
    __builtin_amdgcn_sched_barrier(0);
  }

  // ---- epilogue: reduce l across halves, normalize, store
  lrow += __shfl_xor(lrow, 32);
  float inv_[16];
#pragma unroll
  for (int r = 0; r < 16; ++r) {
    int qr = (r & 3) + 8 * (r >> 2) + 4 * hh;
    inv_[r] = 1.0f / __shfl(lrow, qr);
  }
#pragma unroll
  for (int db = 0; db < 4; ++db) {
#pragma unroll
    for (int r = 0; r < 16; ++r) {
      int qr = (r & 3) + 8 * (r >> 2) + 4 * hh;
      O[qbase + (size_t)(q0w + qr) * D_DIM + db * 32 + l31] =
          f2bf(oacc[db][r] * inv_[r]);
    }
  }
}

// ---------------- launch ----------------
extern "C" void kernel_launch(void* const* d_in, const int* in_sizes, int n_in,
                              void* d_out, int out_size, void* d_ws, size_t ws_size,
                              hipStream_t stream) {
  const float* x   = (const float*)d_in[0];
  const float* fc  = (const float*)d_in[1];
  const float* fs  = (const float*)d_in[2];
  const float* qw  = (const float*)d_in[3];
  const float* qb  = (const float*)d_in[4];
  const float* kw  = (const float*)d_in[5];
  const float* kb  = (const float*)d_in[6];
  const float* vw  = (const float*)d_in[7];
  const float* vb  = (const float*)d_in[8];
  const float* ow  = (const float*)d_in[9];
  const float* ob  = (const float*)d_in[10];
  const float* qnw = (const float*)d_in[11];
  const float* knw = (const float*)d_in[12];
  float* out = (float*)d_out;

  const size_t MSD = (size_t)MROWS * D_DIM;
  const size_t WSZ = (size_t)D_DIM * D_DIM;
  char* ws = (char*)d_ws;
  unsigned short* xb   = (unsigned short*)ws; ws += MSD * 2;
  unsigned short* qwb  = (unsigned short*)ws; ws += WSZ * 2;
  unsigned short* kwb  = (unsigned short*)ws; ws += WSZ * 2;
  unsigned short* vwb  = (unsigned short*)ws; ws += WSZ * 2;
  unsigned short* owb  = (unsigned short*)ws; ws += WSZ * 2;
  unsigned short* qpre = (unsigned short*)ws; ws += MSD * 2;  // bf16 pre-norm
  unsigned short* qb16 = (unsigned short*)ws; ws += MSD * 2;
  unsigned short* kb16 = (unsigned short*)ws; ws += MSD * 2;  // Kh[b][h][s][d]
  unsigned short* vt16 = (unsigned short*)ws; ws += MSD * 2;  // Vt2[b][h][s/64][d][s%64]
  unsigned short* ob16 = (unsigned short*)ws; ws += MSD * 2;

  cast_all<<<2048, 256, 0, stream>>>(x, qw, kw, vw, ow, xb, qwb, kwb, vwb, owb);

  dim3 ggrid((D_DIM / 128) * (MROWS / 128));   // 512, 1D + XCD swizzle
  gemm_bt<2><<<ggrid, 256, 0, stream>>>(xb, vwb, vb, vt16, MROWS, D_DIM, D_DIM);
  gemm_bt<1><<<ggrid, 256, 0, stream>>>(xb, qwb, qb, qpre, MROWS, D_DIM, D_DIM);
  const float qscale = 0.08838834764831845f * 1.4426950408889634f;
  norm_rope<0><<<MROWS, 256, 0, stream>>>(qpre, qnw, fc, fs, qb16, qscale);
  gemm_bt<1><<<ggrid, 256, 0, stream>>>(xb, kwb, kb, qpre, MROWS, D_DIM, D_DIM);
  norm_rope<1><<<MROWS, 256, 0, stream>>>(qpre, knw, fc, fs, kb16, 1.0f);

  attn_kernel<<<dim3(S_LEN / 128 * NHEAD * B_SZ), 256, 0, stream>>>(qb16, kb16, vt16, ob16);

  gemm_bt<0><<<ggrid, 256, 0, stream>>>(ob16, owb, ob, out, MROWS, D_DIM, D_DIM);
}

// Round 9
// 384.654 us; speedup vs baseline: 1.0551x; 1.0551x over previous
//
#include <hip/hip_runtime.h>
#include <stdint.h>

#define B_SZ 2
#define S_LEN 2048
#define D_DIM 2048
#define NHEAD 16
#define HD 128
#define HALF 64
#define MROWS (B_SZ * S_LEN)   // 4096

typedef __attribute__((ext_vector_type(8))) __bf16 bf16x8;
typedef __attribute__((ext_vector_type(8))) unsigned short u16x8;
typedef __attribute__((ext_vector_type(4))) float f32x4;
typedef __attribute__((ext_vector_type(16))) float f32x16;
typedef __attribute__((ext_vector_type(4))) unsigned int u32x4;

__device__ inline unsigned short f2bf(float x) {
  union { float f; uint32_t u; } c; c.f = x;
  uint32_t r = (c.u + 0x7fffu + ((c.u >> 16) & 1u)) >> 16;
  return (unsigned short)r;
}

__device__ inline float bf2f(unsigned short b) {
  union { uint32_t u; float f; } c; c.u = (uint32_t)b << 16;
  return c.f;
}

__device__ inline void gll16(const void* g, void* l) {
  __builtin_amdgcn_global_load_lds(
      (const __attribute__((address_space(1))) void*)g,
      (__attribute__((address_space(3))) void*)l,
      16, 0, 0);
}

// ---------------- fused cast f32 -> bf16 for x + 4 weight matrices ----------------
__global__ void cast_all(const float* __restrict__ x,
                         const float* __restrict__ qw, const float* __restrict__ kw,
                         const float* __restrict__ vw, const float* __restrict__ ow,
                         unsigned short* __restrict__ xb,
                         unsigned short* __restrict__ qwb, unsigned short* __restrict__ kwb,
                         unsigned short* __restrict__ vwb, unsigned short* __restrict__ owb) {
  const int n_x = (MROWS * D_DIM) / 4;
  const int n_w = (D_DIM * D_DIM) / 4;      // == 1<<20
  const int total = n_x + 4 * n_w;
  int i = blockIdx.x * blockDim.x + threadIdx.x;
  int stride = gridDim.x * blockDim.x;
  for (; i < total; i += stride) {
    const float* src; unsigned short* dst; int off;
    if (i < n_x) { src = x; dst = xb; off = i; }
    else {
      int j = i - n_x;
      int seg = j >> 20;
      off = j & (n_w - 1);
      src = seg == 0 ? qw : seg == 1 ? kw : seg == 2 ? vw : ow;
      dst = seg == 0 ? qwb : seg == 1 ? kwb : seg == 2 ? vwb : owb;
    }
    float4 v = reinterpret_cast<const float4*>(src)[off];
    ushort4 o;
    o.x = f2bf(v.x); o.y = f2bf(v.y); o.z = f2bf(v.z); o.w = f2bf(v.w);
    reinterpret_cast<ushort4*>(dst)[off] = o;
  }
}

// ---------------- GEMM: C[i,j] = sum_k A[i,k]*Bt[j,k] + bias[j] ----------------
// MODE 0: fp32 linear. MODE 1: bf16 linear.
// MODE 2: bf16 s-tiled per-head transpose: Vt2[b][h][s/64][d][s%64]
template <int MODE>
__global__ __launch_bounds__(256) void gemm_bt(
    const unsigned short* __restrict__ A, const unsigned short* __restrict__ Bt,
    const float* __restrict__ bias, void* __restrict__ Cv,
    int M, int N, int K) {
  __shared__ __align__(16) unsigned short As[128 * 32];
  __shared__ __align__(16) unsigned short Bs[128 * 32];
  const int tid = threadIdx.x;
  const int lane = tid & 63;
  const int wave = tid >> 6;
  const int nbn = N >> 7;
  const int chunk = gridDim.x >> 3;
  const int lin = (blockIdx.x & 7) * chunk + (blockIdx.x >> 3);
  const int bm = lin / nbn, bn = lin - bm * nbn;
  const int wr = wave >> 1, wc = wave & 1;
  const int lm = lane & 15, lg = lane >> 4;

  f32x4 acc[4][4] = {};

  for (int k0 = 0; k0 < K; k0 += 32) {
    __syncthreads();
#pragma unroll
    for (int j = 0; j < 2; ++j) {
      int ob = wave * 2048 + j * 1024;
      int o = ob + lane * 16;
      int row = o >> 6;
      int col = (o & 63) >> 1;
      const unsigned short* ga = A + (size_t)(bm * 128 + row) * K + k0 + col;
      gll16(ga, (char*)As + ob);
      const unsigned short* gb = Bt + (size_t)(bn * 128 + row) * K + k0 + col;
      gll16(gb, (char*)Bs + ob);
    }
    __syncthreads();

    bf16x8 af[4], bfr[4];
#pragma unroll
    for (int mi = 0; mi < 4; ++mi)
      af[mi] = *reinterpret_cast<const bf16x8*>(
          &As[(wr * 64 + mi * 16 + lm) * 32 + lg * 8]);
#pragma unroll
    for (int ni = 0; ni < 4; ++ni)
      bfr[ni] = *reinterpret_cast<const bf16x8*>(
          &Bs[(wc * 64 + ni * 16 + lm) * 32 + lg * 8]);
#pragma unroll
    for (int mi = 0; mi < 4; ++mi)
#pragma unroll
      for (int ni = 0; ni < 4; ++ni)
        acc[mi][ni] = __builtin_amdgcn_mfma_f32_16x16x32_bf16(
            af[mi], bfr[ni], acc[mi][ni], 0, 0, 0);
  }

#pragma unroll
  for (int ni = 0; ni < 4; ++ni) {
    int col = bn * 128 + wc * 64 + ni * 16 + lm;
    float bv = bias[col];
    if constexpr (MODE == 2) {
      int h = col >> 7, d = col & (HD - 1);
#pragma unroll
      for (int mi = 0; mi < 4; ++mi) {
        int row0 = bm * 128 + wr * 64 + mi * 16 + lg * 4;
        int b = row0 >> 11, s0 = row0 & (S_LEN - 1);
        ushort4 o;
        o.x = f2bf(acc[mi][ni][0] + bv);
        o.y = f2bf(acc[mi][ni][1] + bv);
        o.z = f2bf(acc[mi][ni][2] + bv);
        o.w = f2bf(acc[mi][ni][3] + bv);
        unsigned short* vt = (unsigned short*)Cv;
        size_t oi = ((((size_t)(b * NHEAD + h) * (S_LEN / 64) + (s0 >> 6)) * HD + d) << 6)
                    + (s0 & 63);
        *reinterpret_cast<ushort4*>(vt + oi) = o;
      }
    } else {
#pragma unroll
      for (int mi = 0; mi < 4; ++mi) {
#pragma unroll
        for (int r = 0; r < 4; ++r) {
          int row = bm * 128 + wr * 64 + mi * 16 + lg * 4 + r;
          float v = acc[mi][ni][r] + bv;
          if constexpr (MODE == 1)
            ((unsigned short*)Cv)[(size_t)row * N + col] = f2bf(v);
          else
            ((float*)Cv)[(size_t)row * N + col] = v;
        }
      }
    }
  }
}

// ---------------- RMSNorm (full D) + RoPE, bf16 in -> bf16 out, * outscale ----------------
// BLOCKED=0: linear [row][D]. BLOCKED=1: head-blocked Kh[b][h][s][d].
template <int BLOCKED>
__global__ __launch_bounds__(256) void norm_rope(
    const unsigned short* __restrict__ h, const float* __restrict__ w,
    const float* __restrict__ cosb, const float* __restrict__ sinb,
    unsigned short* __restrict__ out, float outscale) {
  const int row = blockIdx.x;
  const int pos = row & (S_LEN - 1);
  const unsigned short* hr = h + (size_t)row * D_DIM;
  const int t = threadIdx.x;
  const int d = t * 8;

  u16x8 hv = *reinterpret_cast<const u16x8*>(hr + d);
  float a[8];
#pragma unroll
  for (int i = 0; i < 8; ++i) a[i] = bf2f(hv[i]);
  float ss = 0.f;
#pragma unroll
  for (int i = 0; i < 8; ++i) ss += a[i] * a[i];
#pragma unroll
  for (int off = 32; off > 0; off >>= 1) ss += __shfl_down(ss, off);
  __shared__ float red[4];
  if ((t & 63) == 0) red[t >> 6] = ss;
  __syncthreads();
  float tot = red[0] + red[1] + red[2] + red[3];
  float inv = rsqrtf(tot * (1.0f / D_DIM) + 1e-6f) * outscale;

  const int p = (d & (HD - 1)) >> 1;
  const float* cp = cosb + pos * HALF + p;
  const float* sp = sinb + pos * HALF + p;
  const float* wp = w + d;

  float c0 = cp[0], c1 = cp[1], c2 = cp[2], c3 = cp[3];
  float s0 = sp[0], s1 = sp[1], s2 = sp[2], s3 = sp[3];
#pragma unroll
  for (int i = 0; i < 8; ++i) a[i] = a[i] * inv * wp[i];
  u16x8 o;
  o[0] = f2bf(a[0] * c0 - a[1] * s0);
  o[1] = f2bf(a[0] * s0 + a[1] * c0);
  o[2] = f2bf(a[2] * c1 - a[3] * s1);
  o[3] = f2bf(a[2] * s1 + a[3] * c1);
  o[4] = f2bf(a[4] * c2 - a[5] * s2);
  o[5] = f2bf(a[4] * s2 + a[5] * c2);
  o[6] = f2bf(a[6] * c3 - a[7] * s3);
  o[7] = f2bf(a[6] * s3 + a[7] * c3);
  if constexpr (BLOCKED) {
    int hh = t >> 4;            // head = d / HD
    int dd = d & (HD - 1);
    size_t oi = (((size_t)((row >> 11) * NHEAD + hh) * S_LEN) + pos) * HD + dd;
    *reinterpret_cast<u16x8*>(out + oi) = o;
  } else {
    *reinterpret_cast<u16x8*>(out + (size_t)row * D_DIM + d) = o;
  }
}

// ---------------- flash attention: 4 waves x 32q (32x32 MFMA), KVBLK=64 ----------------
// 48KB LDS (K dbuf 32KB + V single 16KB); NO min-waves launch bound — the
// natural ~160 VGPR allocation gives 3 blocks/CU by both LDS and VGPR
// (round-8 lesson: forcing 3 waves/EU spilled oacc to scratch, +80MB HBM).
// Per tile: issue V(t), K(t+1); vmcnt(8) drains K(t); after QK+softmax
// vmcnt(4) drains V(t), K(t+1) stays in flight; 3 barriers/tile.
// Swapped QK^T; in-register P via cvt_pk+permlane; defer-max (THR=8, exp2).
__global__ __launch_bounds__(256) void attn_kernel(
    const unsigned short* __restrict__ Q, const unsigned short* __restrict__ Kh,
    const unsigned short* __restrict__ Vt, unsigned short* __restrict__ O) {
  const int idx = blockIdx.x;
  const int swz = (idx & 7) * 64 + (idx >> 3);   // 512 blocks, 64/XCD
  const int qb = swz & 15;
  const int h = (swz >> 4) & 15;
  const int b = swz >> 8;

  const int tid = threadIdx.x;
  const int lane = tid & 63;
  const int wave = tid >> 6;
  const int l31 = lane & 31;
  const int hh = lane >> 5;

  const size_t qbase = (size_t)b * S_LEN * D_DIM + (size_t)h * HD;   // linear Q/O
  const size_t hbase = (size_t)(b * NHEAD + h) * S_LEN * HD;         // blocked K/V
  const int q0w = qb * 128 + wave * 32;

  __shared__ __align__(16) unsigned short Ks[2 * 64 * 128];  // 2 x 16KB (dbuf)
  __shared__ __align__(16) unsigned short Vs[128 * 64];      // 1 x 16KB

  bf16x8 qf[8];
#pragma unroll
  for (int ds_ = 0; ds_ < 8; ++ds_)
    qf[ds_] = *reinterpret_cast<const bf16x8*>(
        Q + qbase + (size_t)(q0w + l31) * D_DIM + ds_ * 16 + hh * 8);

  f32x16 oacc[4] = {};
  float mrow = -1e30f, lrow = 0.f;

  const int pbase = wave * 1024 + (lane << 4);

  auto stageK = [&](int buf, int tix) {
    const unsigned short* ksrc = Kh + hbase + (size_t)tix * (64 * HD);
#pragma unroll
    for (int j = 0; j < 4; ++j) {
      int p = pbase + j * 4096;
      int kr = p >> 8;                       // K row (256B rows)
      int kc = ((p >> 4) & 15) ^ (kr & 7);   // pre-swizzled source chunk
      gll16(ksrc + kr * 128 + kc * 8, (char*)Ks + buf * 16384 + p);
    }
  };
  auto stageV = [&](int tix) {
    const unsigned short* vsrc = Vt + hbase + (size_t)tix * (64 * HD);
#pragma unroll
    for (int j = 0; j < 4; ++j) {
      int p = pbase + j * 4096;
      int vr = p >> 7;                       // V d-row (128B rows)
      int vc = ((p >> 4) & 7) ^ (vr & 7);
      gll16(vsrc + vr * 64 + vc * 8, (char*)Vs + p);
    }
  };

  stageK(0, 0);   // 4 K-loads in flight

  const int NT = S_LEN / 64;
  for (int t = 0; t < NT; ++t) {
    const int cur = t & 1;
    stageV(t);                                          // +4 (V(t))
    stageK(cur ^ 1, (t + 1 < NT) ? t + 1 : t);          // +4 (K(t+1))
    asm volatile("s_waitcnt vmcnt(8)" ::: "memory");    // drain K(t) (oldest 4)
    __builtin_amdgcn_sched_barrier(0);
    __builtin_amdgcn_s_barrier();          // BAR1: K(t) visible to all waves
    __builtin_amdgcn_sched_barrier(0);

    // ---- QK^T swapped: pA = P[k=0..31][q], pB = P[k=32..63][q], q col = l31
    const char* kbp = (const char*)Ks + cur * 16384;
    f32x16 pA = {}, pB = {};
    __builtin_amdgcn_s_setprio(1);
#pragma unroll
    for (int ds_ = 0; ds_ < 8; ++ds_) {
      bf16x8 k0 = *reinterpret_cast<const bf16x8*>(
          kbp + l31 * 256 + (((ds_ * 2 + hh) ^ (l31 & 7)) << 4));
      bf16x8 k1 = *reinterpret_cast<const bf16x8*>(
          kbp + (32 + l31) * 256 + (((ds_ * 2 + hh) ^ (l31 & 7)) << 4));
      pA = __builtin_amdgcn_mfma_f32_32x32x16_bf16(k0, qf[ds_], pA, 0, 0, 0);
      pB = __builtin_amdgcn_mfma_f32_32x32x16_bf16(k1, qf[ds_], pB, 0, 0, 0);
    }
    __builtin_amdgcn_s_setprio(0);

    // ---- online softmax (per-lane q-row = l31)
    float mx = pA[0];
#pragma unroll
    for (int r = 1; r < 16; ++r) mx = fmaxf(mx, pA[r]);
#pragma unroll
    for (int r = 0; r < 16; ++r) mx = fmaxf(mx, pB[r]);
    mx = fmaxf(mx, __shfl_xor(mx, 32));
    if (__any(mx > mrow + 8.0f)) {          // defer-max rescale (rare)
      float nm = fmaxf(mrow, mx);
      float alpha = exp2f(mrow - nm);
      mrow = nm;
      lrow *= alpha;
#pragma unroll
      for (int r = 0; r < 16; ++r) {
        int qr = (r & 3) + 8 * (r >> 2) + 4 * hh;
        float av = __shfl(alpha, qr);
        oacc[0][r] *= av; oacc[1][r] *= av; oacc[2][r] *= av; oacc[3][r] *= av;
      }
    }
    float ls = 0.f;
#pragma unroll
    for (int r = 0; r < 16; ++r) { float v = exp2f(pA[r] - mrow); pA[r] = v; ls += v; }
#pragma unroll
    for (int r = 0; r < 16; ++r) { float v = exp2f(pB[r] - mrow); pB[r] = v; ls += v; }
    lrow += ls;

    // ---- P -> bf16 A-frags in-register (cvt_pk + permlane32_swap)
    uint32_t w[16];
#pragma unroll
    for (int gg = 0; gg < 4; ++gg) {
      uint32_t lo, hi;
      float a0 = pA[4 * gg], a1 = pA[4 * gg + 1], a2 = pA[4 * gg + 2], a3 = pA[4 * gg + 3];
      asm("v_cvt_pk_bf16_f32 %0, %1, %2" : "=v"(lo) : "v"(a0), "v"(a1));
      asm("v_cvt_pk_bf16_f32 %0, %1, %2" : "=v"(hi) : "v"(a2), "v"(a3));
      w[gg * 2] = lo; w[gg * 2 + 1] = hi;
    }
#pragma unroll
    for (int gg = 0; gg < 4; ++gg) {
      uint32_t lo, hi;
      float a0 = pB[4 * gg], a1 = pB[4 * gg + 1], a2 = pB[4 * gg + 2], a3 = pB[4 * gg + 3];
      asm("v_cvt_pk_bf16_f32 %0, %1, %2" : "=v"(lo) : "v"(a0), "v"(a1));
      asm("v_cvt_pk_bf16_f32 %0, %1, %2" : "=v"(hi) : "v"(a2), "v"(a3));
      w[8 + gg * 2] = lo; w[8 + gg * 2 + 1] = hi;
    }
    bf16x8 pa[4];
#pragma unroll
    for (int s = 0; s < 4; ++s) {
      int wb = (s >> 1) * 8 + (s & 1) * 4;
      uint32_t le = w[wb], he = w[wb + 1], lo_ = w[wb + 2], ho = w[wb + 3];
      asm("v_permlane32_swap_b32 %0, %1" : "+v"(le), "+v"(lo_));
      asm("v_permlane32_swap_b32 %0, %1" : "+v"(he), "+v"(ho));
      u32x4 fr = {le, he, lo_, ho};
      pa[s] = __builtin_bit_cast(bf16x8, fr);
    }

    // ---- wait V(t) (drains to 4: K(t+1) stays in flight), then barrier
    asm volatile("s_waitcnt vmcnt(4)" ::: "memory");
    __builtin_amdgcn_sched_barrier(0);
    __builtin_amdgcn_s_barrier();          // BAR-mid: V(t) visible to all waves
    __builtin_amdgcn_sched_barrier(0);

    // ---- PV: O[q][d] += P[q][k] V[k][d]
    const char* vbp = (const char*)Vs;
    __builtin_amdgcn_s_setprio(1);
#pragma unroll
    for (int db = 0; db < 4; ++db) {
      int d = db * 32 + l31;
#pragma unroll
      for (int ks = 0; ks < 4; ++ks) {
        bf16x8 vv = *reinterpret_cast<const bf16x8*>(
            vbp + d * 128 + (((ks * 2 + hh) ^ (d & 7)) << 4));
        oacc[db] = __builtin_amdgcn_mfma_f32_32x32x16_bf16(pa[ks], vv, oacc[db], 0, 0, 0);
      }
    }
    __builtin_amdgcn_s_setprio(0);

    __builtin_amdgcn_sched_barrier(0);
    __builtin_amdgcn_s_barrier();          // BAR2: Vs + Ks[cur] reads done
    __builtin_amdgcn_sched_barrier(0);
  }

  // ---- epilogue: reduce l across halves, normalize, store
  lrow += __shfl_xor(lrow, 32);
  float inv_[16];
#pragma unroll
  for (int r = 0; r < 16; ++r) {
    int qr = (r & 3) + 8 * (r >> 2) + 4 * hh;
    inv_[r] = 1.0f / __shfl(lrow, qr);
  }
#pragma unroll
  for (int db = 0; db < 4; ++db) {
#pragma unroll
    for (int r = 0; r < 16; ++r) {
      int qr = (r & 3) + 8 * (r >> 2) + 4 * hh;
      O[qbase + (size_t)(q0w + qr) * D_DIM + db * 32 + l31] =
          f2bf(oacc[db][r] * inv_[r]);
    }
  }
}

// ---------------- launch ----------------
extern "C" void kernel_launch(void* const* d_in, const int* in_sizes, int n_in,
                              void* d_out, int out_size, void* d_ws, size_t ws_size,
                              hipStream_t stream) {
  const float* x   = (const float*)d_in[0];
  const float* fc  = (const float*)d_in[1];
  const float* fs  = (const float*)d_in[2];
  const float* qw  = (const float*)d_in[3];
  const float* qb  = (const float*)d_in[4];
  const float* kw  = (const float*)d_in[5];
  const float* kb  = (const float*)d_in[6];
  const float* vw  = (const float*)d_in[7];
  const float* vb  = (const float*)d_in[8];
  const float* ow  = (const float*)d_in[9];
  const float* ob  = (const float*)d_in[10];
  const float* qnw = (const float*)d_in[11];
  const float* knw = (const float*)d_in[12];
  float* out = (float*)d_out;

  const size_t MSD = (size_t)MROWS * D_DIM;
  const size_t WSZ = (size_t)D_DIM * D_DIM;
  char* ws = (char*)d_ws;
  unsigned short* xb   = (unsigned short*)ws; ws += MSD * 2;
  unsigned short* qwb  = (unsigned short*)ws; ws += WSZ * 2;
  unsigned short* kwb  = (unsigned short*)ws; ws += WSZ * 2;
  unsigned short* vwb  = (unsigned short*)ws; ws += WSZ * 2;
  unsigned short* owb  = (unsigned short*)ws; ws += WSZ * 2;
  unsigned short* qpre = (unsigned short*)ws; ws += MSD * 2;  // bf16 pre-norm
  unsigned short* qb16 = (unsigned short*)ws; ws += MSD * 2;
  unsigned short* kb16 = (unsigned short*)ws; ws += MSD * 2;  // Kh[b][h][s][d]
  unsigned short* vt16 = (unsigned short*)ws; ws += MSD * 2;  // Vt2[b][h][s/64][d][s%64]
  unsigned short* ob16 = (unsigned short*)ws; ws += MSD * 2;

  cast_all<<<2048, 256, 0, stream>>>(x, qw, kw, vw, ow, xb, qwb, kwb, vwb, owb);

  dim3 ggrid((D_DIM / 128) * (MROWS / 128));   // 512, 1D + XCD swizzle
  gemm_bt<2><<<ggrid, 256, 0, stream>>>(xb, vwb, vb, vt16, MROWS, D_DIM, D_DIM);
  gemm_bt<1><<<ggrid, 256, 0, stream>>>(xb, qwb, qb, qpre, MROWS, D_DIM, D_DIM);
  const float qscale = 0.08838834764831845f * 1.4426950408889634f;
  norm_rope<0><<<MROWS, 256, 0, stream>>>(qpre, qnw, fc, fs, qb16, qscale);
  gemm_bt<1><<<ggrid, 256, 0, stream>>>(xb, kwb, kb, qpre, MROWS, D_DIM, D_DIM);
  norm_rope<1><<<MROWS, 256, 0, stream>>>(qpre, knw, fc, fs, kb16, 1.0f);

  attn_kernel<<<dim3(S_LEN / 128 * NHEAD * B_SZ), 256, 0, stream>>>(qb16, kb16, vt16, ob16);

  gemm_bt<0><<<ggrid, 256, 0, stream>>>(ob16, owb, ob, out, MROWS, D_DIM, D_DIM);
}

// Round 10
// 339.630 us; speedup vs baseline: 1.1950x; 1.1326x over previous
//
#include <hip/hip_runtime.h>
#include <stdint.h>

#define B_SZ 2
#define S_LEN 2048
#define D_DIM 2048
#define NHEAD 16
#define HD 128
#define HALF 64
#define MROWS (B_SZ * S_LEN)   // 4096

typedef __attribute__((ext_vector_type(8))) __bf16 bf16x8;
typedef __attribute__((ext_vector_type(8))) unsigned short u16x8;
typedef __attribute__((ext_vector_type(4))) float f32x4;
typedef __attribute__((ext_vector_type(16))) float f32x16;
typedef __attribute__((ext_vector_type(4))) unsigned int u32x4;

__device__ inline unsigned short f2bf(float x) {
  union { float f; uint32_t u; } c; c.f = x;
  uint32_t r = (c.u + 0x7fffu + ((c.u >> 16) & 1u)) >> 16;
  return (unsigned short)r;
}

__device__ inline float bf2f(unsigned short b) {
  union { uint32_t u; float f; } c; c.u = (uint32_t)b << 16;
  return c.f;
}

__device__ inline void gll16(const void* g, void* l) {
  __builtin_amdgcn_global_load_lds(
      (const __attribute__((address_space(1))) void*)g,
      (__attribute__((address_space(3))) void*)l,
      16, 0, 0);
}

// ---------------- fused cast f32 -> bf16 for x + 4 weight matrices ----------------
__global__ void cast_all(const float* __restrict__ x,
                         const float* __restrict__ qw, const float* __restrict__ kw,
                         const float* __restrict__ vw, const float* __restrict__ ow,
                         unsigned short* __restrict__ xb,
                         unsigned short* __restrict__ qwb, unsigned short* __restrict__ kwb,
                         unsigned short* __restrict__ vwb, unsigned short* __restrict__ owb) {
  const int n_x = (MROWS * D_DIM) / 4;
  const int n_w = (D_DIM * D_DIM) / 4;      // == 1<<20
  const int total = n_x + 4 * n_w;
  int i = blockIdx.x * blockDim.x + threadIdx.x;
  int stride = gridDim.x * blockDim.x;
  for (; i < total; i += stride) {
    const float* src; unsigned short* dst; int off;
    if (i < n_x) { src = x; dst = xb; off = i; }
    else {
      int j = i - n_x;
      int seg = j >> 20;
      off = j & (n_w - 1);
      src = seg == 0 ? qw : seg == 1 ? kw : seg == 2 ? vw : ow;
      dst = seg == 0 ? qwb : seg == 1 ? kwb : seg == 2 ? vwb : owb;
    }
    float4 v = reinterpret_cast<const float4*>(src)[off];
    ushort4 o;
    o.x = f2bf(v.x); o.y = f2bf(v.y); o.z = f2bf(v.z); o.w = f2bf(v.w);
    reinterpret_cast<ushort4*>(dst)[off] = o;
  }
}

// ---------------- GEMM: C[i,j] = sum_k A[i,k]*Bt[j,k] + bias[j] ----------------
// MODE 0: fp32 linear. MODE 1: bf16 linear.
// MODE 2: bf16 s-tiled per-head transpose: Vt2[b][h][s/64][d][s%64]
template <int MODE>
__global__ __launch_bounds__(256) void gemm_bt(
    const unsigned short* __restrict__ A, const unsigned short* __restrict__ Bt,
    const float* __restrict__ bias, void* __restrict__ Cv,
    int M, int N, int K) {
  __shared__ __align__(16) unsigned short As[128 * 32];
  __shared__ __align__(16) unsigned short Bs[128 * 32];
  const int tid = threadIdx.x;
  const int lane = tid & 63;
  const int wave = tid >> 6;
  const int nbn = N >> 7;
  const int chunk = gridDim.x >> 3;
  const int lin = (blockIdx.x & 7) * chunk + (blockIdx.x >> 3);
  const int bm = lin / nbn, bn = lin - bm * nbn;
  const int wr = wave >> 1, wc = wave & 1;
  const int lm = lane & 15, lg = lane >> 4;

  f32x4 acc[4][4] = {};

  for (int k0 = 0; k0 < K; k0 += 32) {
    __syncthreads();
#pragma unroll
    for (int j = 0; j < 2; ++j) {
      int ob = wave * 2048 + j * 1024;
      int o = ob + lane * 16;
      int row = o >> 6;
      int col = (o & 63) >> 1;
      const unsigned short* ga = A + (size_t)(bm * 128 + row) * K + k0 + col;
      gll16(ga, (char*)As + ob);
      const unsigned short* gb = Bt + (size_t)(bn * 128 + row) * K + k0 + col;
      gll16(gb, (char*)Bs + ob);
    }
    __syncthreads();

    bf16x8 af[4], bfr[4];
#pragma unroll
    for (int mi = 0; mi < 4; ++mi)
      af[mi] = *reinterpret_cast<const bf16x8*>(
          &As[(wr * 64 + mi * 16 + lm) * 32 + lg * 8]);
#pragma unroll
    for (int ni = 0; ni < 4; ++ni)
      bfr[ni] = *reinterpret_cast<const bf16x8*>(
          &Bs[(wc * 64 + ni * 16 + lm) * 32 + lg * 8]);
#pragma unroll
    for (int mi = 0; mi < 4; ++mi)
#pragma unroll
      for (int ni = 0; ni < 4; ++ni)
        acc[mi][ni] = __builtin_amdgcn_mfma_f32_16x16x32_bf16(
            af[mi], bfr[ni], acc[mi][ni], 0, 0, 0);
  }

#pragma unroll
  for (int ni = 0; ni < 4; ++ni) {
    int col = bn * 128 + wc * 64 + ni * 16 + lm;
    float bv = bias[col];
    if constexpr (MODE == 2) {
      int h = col >> 7, d = col & (HD - 1);
#pragma unroll
      for (int mi = 0; mi < 4; ++mi) {
        int row0 = bm * 128 + wr * 64 + mi * 16 + lg * 4;
        int b = row0 >> 11, s0 = row0 & (S_LEN - 1);
        ushort4 o;
        o.x = f2bf(acc[mi][ni][0] + bv);
        o.y = f2bf(acc[mi][ni][1] + bv);
        o.z = f2bf(acc[mi][ni][2] + bv);
        o.w = f2bf(acc[mi][ni][3] + bv);
        unsigned short* vt = (unsigned short*)Cv;
        size_t oi = ((((size_t)(b * NHEAD + h) * (S_LEN / 64) + (s0 >> 6)) * HD + d) << 6)
                    + (s0 & 63);
        *reinterpret_cast<ushort4*>(vt + oi) = o;
      }
    } else {
#pragma unroll
      for (int mi = 0; mi < 4; ++mi) {
#pragma unroll
        for (int r = 0; r < 4; ++r) {
          int row = bm * 128 + wr * 64 + mi * 16 + lg * 4 + r;
          float v = acc[mi][ni][r] + bv;
          if constexpr (MODE == 1)
            ((unsigned short*)Cv)[(size_t)row * N + col] = f2bf(v);
          else
            ((float*)Cv)[(size_t)row * N + col] = v;
        }
      }
    }
  }
}

// ---------------- RMSNorm (full D) + RoPE, bf16 in -> bf16 out, * outscale ----------------
// BLOCKED=0: linear [row][D]. BLOCKED=1: head-blocked Kh[b][h][s][d].
template <int BLOCKED>
__global__ __launch_bounds__(256) void norm_rope(
    const unsigned short* __restrict__ h, const float* __restrict__ w,
    const float* __restrict__ cosb, const float* __restrict__ sinb,
    unsigned short* __restrict__ out, float outscale) {
  const int row = blockIdx.x;
  const int pos = row & (S_LEN - 1);
  const unsigned short* hr = h + (size_t)row * D_DIM;
  const int t = threadIdx.x;
  const int d = t * 8;

  u16x8 hv = *reinterpret_cast<const u16x8*>(hr + d);
  float a[8];
#pragma unroll
  for (int i = 0; i < 8; ++i) a[i] = bf2f(hv[i]);
  float ss = 0.f;
#pragma unroll
  for (int i = 0; i < 8; ++i) ss += a[i] * a[i];
#pragma unroll
  for (int off = 32; off > 0; off >>= 1) ss += __shfl_down(ss, off);
  __shared__ float red[4];
  if ((t & 63) == 0) red[t >> 6] = ss;
  __syncthreads();
  float tot = red[0] + red[1] + red[2] + red[3];
  float inv = rsqrtf(tot * (1.0f / D_DIM) + 1e-6f) * outscale;

  const int p = (d & (HD - 1)) >> 1;
  const float* cp = cosb + pos * HALF + p;
  const float* sp = sinb + pos * HALF + p;
  const float* wp = w + d;

  float c0 = cp[0], c1 = cp[1], c2 = cp[2], c3 = cp[3];
  float s0 = sp[0], s1 = sp[1], s2 = sp[2], s3 = sp[3];
#pragma unroll
  for (int i = 0; i < 8; ++i) a[i] = a[i] * inv * wp[i];
  u16x8 o;
  o[0] = f2bf(a[0] * c0 - a[1] * s0);
  o[1] = f2bf(a[0] * s0 + a[1] * c0);
  o[2] = f2bf(a[2] * c1 - a[3] * s1);
  o[3] = f2bf(a[2] * s1 + a[3] * c1);
  o[4] = f2bf(a[4] * c2 - a[5] * s2);
  o[5] = f2bf(a[4] * s2 + a[5] * c2);
  o[6] = f2bf(a[6] * c3 - a[7] * s3);
  o[7] = f2bf(a[6] * s3 + a[7] * c3);
  if constexpr (BLOCKED) {
    int hh = t >> 4;            // head = d / HD
    int dd = d & (HD - 1);
    size_t oi = (((size_t)((row >> 11) * NHEAD + hh) * S_LEN) + pos) * HD + dd;
    *reinterpret_cast<u16x8*>(out + oi) = o;
  } else {
    *reinterpret_cast<u16x8*>(out + (size_t)row * D_DIM + d) = o;
  }
}

// ---------------- flash attention: 8 waves x 32q (QBLK=256), KVBLK=64 ----------------
// grid = 256 = exactly 1 block/CU -> 8 waves/CU guaranteed; K/V staged ONCE
// per CU per tile (8 waves share). 48KB LDS: K dbuf 32KB + V single 16KB.
// Full-rank XOR swizzle f(r) = (r&7)^((r>>3)&7) on stage-source AND read
// (kills the 4-way bank conflict of the row&7-only swizzle).
// Per tile: issue V(t) (+2), K(t+1) (+2); vmcnt(4) drains K(t); after
// QK+softmax vmcnt(2) drains V(t), K(t+1) stays in flight; 3 barriers.
// Swapped QK^T; tree-reduced softmax; in-register P via cvt_pk+permlane;
// defer-max (THR=8, exp2 domain). NO min-waves bound (round-8 spill lesson).
__global__ __launch_bounds__(512) void attn_kernel(
    const unsigned short* __restrict__ Q, const unsigned short* __restrict__ Kh,
    const unsigned short* __restrict__ Vt, unsigned short* __restrict__ O) {
  const int idx = blockIdx.x;
  const int swz = (idx & 7) * 32 + (idx >> 3);   // 256 blocks, 32/XCD (4 heads)
  const int qb = swz & 7;
  const int h = (swz >> 3) & 15;
  const int b = swz >> 7;

  const int tid = threadIdx.x;
  const int lane = tid & 63;
  const int wave = tid >> 6;          // 0..7
  const int l31 = lane & 31;
  const int hh = lane >> 5;

  const size_t qbase = (size_t)b * S_LEN * D_DIM + (size_t)h * HD;   // linear Q/O
  const size_t hbase = (size_t)(b * NHEAD + h) * S_LEN * HD;         // blocked K/V
  const int q0w = qb * 256 + wave * 32;

  __shared__ __align__(16) unsigned short Ks[2 * 64 * 128];  // 2 x 16KB (dbuf)
  __shared__ __align__(16) unsigned short Vs[128 * 64];      // 1 x 16KB

  bf16x8 qf[8];
#pragma unroll
  for (int ds_ = 0; ds_ < 8; ++ds_)
    qf[ds_] = *reinterpret_cast<const bf16x8*>(
        Q + qbase + (size_t)(q0w + l31) * D_DIM + ds_ * 16 + hh * 8);

  f32x16 oacc[4] = {};
  float mrow = -1e30f, lrow = 0.f;

  const int pbase = wave * 1024 + (lane << 4);   // 8KB per j-step, j in {0,1}

  auto stageK = [&](int buf, int tix) {
    const unsigned short* ksrc = Kh + hbase + (size_t)tix * (64 * HD);
#pragma unroll
    for (int j = 0; j < 2; ++j) {
      int p = pbase + j * 8192;
      int kr = p >> 8;                                   // row 0..63 (256B rows)
      int kc = ((p >> 4) & 15) ^ ((kr & 7) ^ ((kr >> 3) & 7));
      gll16(ksrc + kr * 128 + kc * 8, (char*)Ks + buf * 16384 + p);
    }
  };
  auto stageV = [&](int tix) {
    const unsigned short* vsrc = Vt + hbase + (size_t)tix * (64 * HD);
#pragma unroll
    for (int j = 0; j < 2; ++j) {
      int p = pbase + j * 8192;
      int vr = p >> 7;                                   // d-row 0..127 (128B rows)
      int vc = ((p >> 4) & 7) ^ (((vr & 7) ^ ((vr >> 3) & 7)) & 7);
      gll16(vsrc + vr * 64 + vc * 8, (char*)Vs + p);
    }
  };

  stageK(0, 0);   // 2 K-loads in flight

  const int NT = S_LEN / 64;
  for (int t = 0; t < NT; ++t) {
    const int cur = t & 1;
    stageV(t);                                          // +2 (V(t))
    stageK(cur ^ 1, (t + 1 < NT) ? t + 1 : t);          // +2 (K(t+1))
    asm volatile("s_waitcnt vmcnt(4)" ::: "memory");    // drain K(t) (oldest 2)
    __builtin_amdgcn_sched_barrier(0);
    __builtin_amdgcn_s_barrier();          // BAR1: K(t) visible to all waves
    __builtin_amdgcn_sched_barrier(0);

    // ---- QK^T swapped: pA = P[k=0..31][q], pB = P[k=32..63][q], q col = l31
    const char* kbp = (const char*)Ks + cur * 16384;
    const int fk0 = (l31 & 7) ^ ((l31 >> 3) & 7);            // f(row) for rows 0..31
    const int fk1 = (l31 & 7) ^ (((l31 + 32) >> 3) & 7);     // f(row+32)
    f32x16 pA = {}, pB = {};
    __builtin_amdgcn_s_setprio(1);
#pragma unroll
    for (int ds_ = 0; ds_ < 8; ++ds_) {
      bf16x8 k0 = *reinterpret_cast<const bf16x8*>(
          kbp + l31 * 256 + (((ds_ * 2 + hh) ^ fk0) << 4));
      bf16x8 k1 = *reinterpret_cast<const bf16x8*>(
          kbp + (32 + l31) * 256 + (((ds_ * 2 + hh) ^ fk1) << 4));
      pA = __builtin_amdgcn_mfma_f32_32x32x16_bf16(k0, qf[ds_], pA, 0, 0, 0);
      pB = __builtin_amdgcn_mfma_f32_32x32x16_bf16(k1, qf[ds_], pB, 0, 0, 0);
    }
    __builtin_amdgcn_s_setprio(0);

    // ---- online softmax (per-lane q-row = l31), tree reductions
    float m8[8];
#pragma unroll
    for (int r = 0; r < 8; ++r)
      m8[r] = fmaxf(fmaxf(pA[r], pA[r + 8]), fmaxf(pB[r], pB[r + 8]));
#pragma unroll
    for (int r = 0; r < 4; ++r) m8[r] = fmaxf(m8[r], m8[r + 4]);
    float mx = fmaxf(fmaxf(m8[0], m8[1]), fmaxf(m8[2], m8[3]));
    mx = fmaxf(mx, __shfl_xor(mx, 32));
    if (__any(mx > mrow + 8.0f)) {          // defer-max rescale (rare)
      float nm = fmaxf(mrow, mx);
      float alpha = exp2f(mrow - nm);
      mrow = nm;
      lrow *= alpha;
#pragma unroll
      for (int r = 0; r < 16; ++r) {
        int qr = (r & 3) + 8 * (r >> 2) + 4 * hh;
        float av = __shfl(alpha, qr);
        oacc[0][r] *= av; oacc[1][r] *= av; oacc[2][r] *= av; oacc[3][r] *= av;
      }
    }
#pragma unroll
    for (int r = 0; r < 16; ++r) pA[r] = exp2f(pA[r] - mrow);
#pragma unroll
    for (int r = 0; r < 16; ++r) pB[r] = exp2f(pB[r] - mrow);
    float s8[8];
#pragma unroll
    for (int r = 0; r < 8; ++r)
      s8[r] = (pA[r] + pA[r + 8]) + (pB[r] + pB[r + 8]);
#pragma unroll
    for (int r = 0; r < 4; ++r) s8[r] += s8[r + 4];
    lrow += (s8[0] + s8[1]) + (s8[2] + s8[3]);

    // ---- P -> bf16 A-frags in-register (cvt_pk + permlane32_swap)
    uint32_t w[16];
#pragma unroll
    for (int gg = 0; gg < 4; ++gg) {
      uint32_t lo, hi;
      float a0 = pA[4 * gg], a1 = pA[4 * gg + 1], a2 = pA[4 * gg + 2], a3 = pA[4 * gg + 3];
      asm("v_cvt_pk_bf16_f32 %0, %1, %2" : "=v"(lo) : "v"(a0), "v"(a1));
      asm("v_cvt_pk_bf16_f32 %0, %1, %2" : "=v"(hi) : "v"(a2), "v"(a3));
      w[gg * 2] = lo; w[gg * 2 + 1] = hi;
    }
#pragma unroll
    for (int gg = 0; gg < 4; ++gg) {
      uint32_t lo, hi;
      float a0 = pB[4 * gg], a1 = pB[4 * gg + 1], a2 = pB[4 * gg + 2], a3 = pB[4 * gg + 3];
      asm("v_cvt_pk_bf16_f32 %0, %1, %2" : "=v"(lo) : "v"(a0), "v"(a1));
      asm("v_cvt_pk_bf16_f32 %0, %1, %2" : "=v"(hi) : "v"(a2), "v"(a3));
      w[8 + gg * 2] = lo; w[8 + gg * 2 + 1] = hi;
    }
    bf16x8 pa[4];
#pragma unroll
    for (int s = 0; s < 4; ++s) {
      int wb = (s >> 1) * 8 + (s & 1) * 4;
      uint32_t le = w[wb], he = w[wb + 1], lo_ = w[wb + 2], ho = w[wb + 3];
      asm("v_permlane32_swap_b32 %0, %1" : "+v"(le), "+v"(lo_));
      asm("v_permlane32_swap_b32 %0, %1" : "+v"(he), "+v"(ho));
      u32x4 fr = {le, he, lo_, ho};
      pa[s] = __builtin_bit_cast(bf16x8, fr);
    }

    // ---- wait V(t) (drains to 2: K(t+1) stays in flight), then barrier
    asm volatile("s_waitcnt vmcnt(2)" ::: "memory");
    __builtin_amdgcn_sched_barrier(0);
    __builtin_amdgcn_s_barrier();          // BAR-mid: V(t) visible to all waves
    __builtin_amdgcn_sched_barrier(0);

    // ---- PV: O[q][d] += P[q][k] V[k][d]
    const char* vbp = (const char*)Vs;
    __builtin_amdgcn_s_setprio(1);
#pragma unroll
    for (int db = 0; db < 4; ++db) {
      int d = db * 32 + l31;
      int fv = (d & 7) ^ ((d >> 3) & 7);
#pragma unroll
      for (int ks = 0; ks < 4; ++ks) {
        bf16x8 vv = *reinterpret_cast<const bf16x8*>(
            vbp + d * 128 + (((ks * 2 + hh) ^ fv) << 4));
        oacc[db] = __builtin_amdgcn_mfma_f32_32x32x16_bf16(pa[ks], vv, oacc[db], 0, 0, 0);
      }
    }
    __builtin_amdgcn_s_setprio(0);

    __builtin_amdgcn_sched_barrier(0);
    __builtin_amdgcn_s_barrier();          // BAR2: Vs + Ks[cur] reads done
    __builtin_amdgcn_sched_barrier(0);
  }

  // ---- epilogue: reduce l across halves, normalize, store
  lrow += __shfl_xor(lrow, 32);
  float inv_[16];
#pragma unroll
  for (int r = 0; r < 16; ++r) {
    int qr = (r & 3) + 8 * (r >> 2) + 4 * hh;
    inv_[r] = 1.0f / __shfl(lrow, qr);
  }
#pragma unroll
  for (int db = 0; db < 4; ++db) {
#pragma unroll
    for (int r = 0; r < 16; ++r) {
      int qr = (r & 3) + 8 * (r >> 2) + 4 * hh;
      O[qbase + (size_t)(q0w + qr) * D_DIM + db * 32 + l31] =
          f2bf(oacc[db][r] * inv_[r]);
    }
  }
}

// ---------------- launch ----------------
extern "C" void kernel_launch(void* const* d_in, const int* in_sizes, int n_in,
                              void* d_out, int out_size, void* d_ws, size_t ws_size,
                              hipStream_t stream) {
  const float* x   = (const float*)d_in[0];
  const float* fc  = (const float*)d_in[1];
  const float* fs  = (const float*)d_in[2];
  const float* qw  = (const float*)d_in[3];
  const float* qb  = (const float*)d_in[4];
  const float* kw  = (const float*)d_in[5];
  const float* kb  = (const float*)d_in[6];
  const float* vw  = (const float*)d_in[7];
  const float* vb  = (const float*)d_in[8];
  const float* ow  = (const float*)d_in[9];
  const float* ob  = (const float*)d_in[10];
  const float* qnw = (const float*)d_in[11];
  const float* knw = (const float*)d_in[12];
  float* out = (float*)d_out;

  const size_t MSD = (size_t)MROWS * D_DIM;
  const size_t WSZ = (size_t)D_DIM * D_DIM;
  char* ws = (char*)d_ws;
  unsigned short* xb   = (unsigned short*)ws; ws += MSD * 2;
  unsigned short* qwb  = (unsigned short*)ws; ws += WSZ * 2;
  unsigned short* kwb  = (unsigned short*)ws; ws += WSZ * 2;
  unsigned short* vwb  = (unsigned short*)ws; ws += WSZ * 2;
  unsigned short* owb  = (unsigned short*)ws; ws += WSZ * 2;
  unsigned short* qpre = (unsigned short*)ws; ws += MSD * 2;  // bf16 pre-norm
  unsigned short* qb16 = (unsigned short*)ws; ws += MSD * 2;
  unsigned short* kb16 = (unsigned short*)ws; ws += MSD * 2;  // Kh[b][h][s][d]
  unsigned short* vt16 = (unsigned short*)ws; ws += MSD * 2;  // Vt2[b][h][s/64][d][s%64]
  unsigned short* ob16 = (unsigned short*)ws; ws += MSD * 2;

  cast_all<<<2048, 256, 0, stream>>>(x, qw, kw, vw, ow, xb, qwb, kwb, vwb, owb);

  dim3 ggrid((D_DIM / 128) * (MROWS / 128));   // 512, 1D + XCD swizzle
  gemm_bt<2><<<ggrid, 256, 0, stream>>>(xb, vwb, vb, vt16, MROWS, D_DIM, D_DIM);
  gemm_bt<1><<<ggrid, 256, 0, stream>>>(xb, qwb, qb, qpre, MROWS, D_DIM, D_DIM);
  const float qscale = 0.08838834764831845f * 1.4426950408889634f;
  norm_rope<0><<<MROWS, 256, 0, stream>>>(qpre, qnw, fc, fs, qb16, qscale);
  gemm_bt<1><<<ggrid, 256, 0, stream>>>(xb, kwb, kb, qpre, MROWS, D_DIM, D_DIM);
  norm_rope<1><<<MROWS, 256, 0, stream>>>(qpre, knw, fc, fs, kb16, 1.0f);

  attn_kernel<<<dim3(S_LEN / 256 * NHEAD * B_SZ), 512, 0, stream>>>(qb16, kb16, vt16, ob16);

  gemm_bt<0><<<ggrid, 256, 0, stream>>>(ob16, owb, ob, out, MROWS, D_DIM, D_DIM);
}